// Round 7
// baseline (260.820 us; speedup 1.0000x reference)
//
#include <hip/hip_runtime.h>
#include <math.h>

#define NH   8
#define HD   64
#define BS   4
#define SEQL 2048
#define DIMX 768
#define EMB  512
#define MROWS (BS*SEQL)
#define NSPLIT 2
#define KSPAN (SEQL/NSPLIT)

typedef __attribute__((ext_vector_type(4))) float          f32x4;
typedef __attribute__((ext_vector_type(8))) __bf16         bf16x8;
typedef __attribute__((ext_vector_type(8))) unsigned short u16x8;
typedef __attribute__((ext_vector_type(4))) unsigned short u16x4;

union BF8 { u16x8 u; bf16x8 b; };

__device__ __forceinline__ unsigned short f2bf(float x) {   // RNE
    unsigned int u = __float_as_uint(x);
    u += 0x7FFFu + ((u >> 16) & 1u);
    return (unsigned short)(u >> 16);
}

#if __has_builtin(__builtin_amdgcn_exp2f)
#define EXP2F(x) __builtin_amdgcn_exp2f(x)
#else
#define EXP2F(x) exp2f(x)
#endif

__device__ __forceinline__ bf16x8 ldb8(const unsigned short* p) {
    return *(const bf16x8*)p;
}

// Async global->LDS, 16B per lane. LDS dest is wave-uniform base + lane*16
// (HW semantics); global src is per-lane.
__device__ __forceinline__ void gload16(const unsigned short* g, unsigned short* l) {
    __builtin_amdgcn_global_load_lds(
        (const __attribute__((address_space(1))) unsigned int*)(const void*)g,
        (__attribute__((address_space(3))) unsigned int*)(void*)l,
        16, 0, 0);
}

// ---------------------------------------------------------------------------
// All 4 weight transposes in ONE dispatch: fp32 [R][C] -> bf16 [C][R].
// ---------------------------------------------------------------------------
__global__ __launch_bounds__(256)
void transpose_w4(const float* __restrict__ w0, const float* __restrict__ w1,
                  const float* __restrict__ w2, const float* __restrict__ w3,
                  unsigned short* __restrict__ o0, unsigned short* __restrict__ o1,
                  unsigned short* __restrict__ o2, unsigned short* __restrict__ o3)
{
    __shared__ float sm[32][33];
    const int which = blockIdx.y;
    const float* in; unsigned short* out; int R, C;
    if      (which == 0) { in = w0; out = o0; R = DIMX; C = EMB;  }
    else if (which == 1) { in = w1; out = o1; R = DIMX; C = EMB;  }
    else if (which == 2) { in = w2; out = o2; R = DIMX; C = EMB;  }
    else                 { in = w3; out = o3; R = EMB;  C = DIMX; }
    const int nbx = C / 32;
    const int rB = (blockIdx.x / nbx) * 32, cB = (blockIdx.x % nbx) * 32;
    const int row = threadIdx.x >> 3, c4 = (threadIdx.x & 7) * 4;
    f32x4 v = *(const f32x4*)&in[(size_t)(rB + row) * C + cB + c4];
    sm[row][c4 + 0] = v[0]; sm[row][c4 + 1] = v[1];
    sm[row][c4 + 2] = v[2]; sm[row][c4 + 3] = v[3];
    __syncthreads();
    u16x4 o;
    o[0] = f2bf(sm[c4 + 0][row]); o[1] = f2bf(sm[c4 + 1][row]);
    o[2] = f2bf(sm[c4 + 2][row]); o[3] = f2bf(sm[c4 + 3][row]);
    *(u16x4*)&out[(size_t)(cB + row) * R + rB + c4] = o;
}

// ---------------------------------------------------------------------------
// Shared GEMM core, ROUND-6: 2-PHASE PREFETCH PIPELINE (T3 minimum recipe).
// 128x128 tile, BK=64, 256 threads (4 waves as 2x2), bf16 A[M,K] @ Bt[N,K]^T.
// LDS is DOUBLE-BUFFERED (2 x 16KB per operand, 64KB total). Per K-step:
//   1. issue tile-(t+1) fp32 A global loads (raw regs, convert deferred)
//      and B gload16s into buf^1  -- latency hides under step 2
//   2. MFMA compute on buf (ds_read_b128, conflict-free via XOR swizzle)
//   3. convert + ds_write A(t+1) into buf^1 (waitcnt lands here, covered)
//   4. ONE __syncthreads (drains B gloads + A ds_writes)   [was 2 barriers]
// R6 counters showed the old 2-barrier serial staging left MfmaUtil at 10%
// with latency exposed inside every K-step.
// B staging keeps rule-#21 both-sides swizzle (linear LDS dest, pre-XORed
// global source column, XORed frag reads).
// A staging FUSED-ON-THE-FLY:
//   AMODE 1: A fp32 [M][lda], cast bf16 RNE during staging (kills cast3).
//   AMODE 2: A[m][k] = f2bf((Op0+Op1) * 1/(l0+l1)) attn split-combine
//            (kills attn_reduce), Opart layout [sp][bh][q][64].
// DIRECT:  acc[mt][nt] = mfma(x, w)  -> row=m, col=n   (V-transposed epilogue)
// !DIRECT: acc[nt][mt] = mfma(w, x)  -> row=n, col=m   (packed row-major out)
// ---------------------------------------------------------------------------
template<bool DIRECT, int AMODE>
__device__ __forceinline__ void gemm_core(
    const float* __restrict__ A, const float* __restrict__ A2,
    const float* __restrict__ lp0, const float* __restrict__ lp1,
    const unsigned short* __restrict__ Bt,
    int K, int lda, int mBase, int nBase,
    unsigned short* __restrict__ smA, unsigned short* __restrict__ smB,  // 2x[128][64] each
    f32x4 (&acc)[4][4])
{
    const int tid = threadIdx.x;
    const int lane = tid & 63, w = tid >> 6;
    const int quad = lane >> 4, lanem = lane & 15;
    const int wm = w >> 1, wn = w & 1;
    // staging map: slab j covers tile rows (w*4+j)*8..+8; lane r8=row-in-slab,
    // ch=16B-chunk; global col chunk pre-XORed by row&7 (rule #21).
    const int r8 = lane >> 3, ch = lane & 7;
    const int swz = ((ch ^ r8) << 3);          // element offset within row
    const int fxor = (lanem & 7);              // frag-read XOR (row&7)

    const f32x4 z4 = {0.f, 0.f, 0.f, 0.f};
    #pragma unroll
    for (int i = 0; i < 4; ++i)
        #pragma unroll
        for (int j = 0; j < 4; ++j) acc[i][j] = z4;

    const int nsteps = K / 64;

    // ---- prologue: stage tile 0 into half 0 (latency exposed once) ----
    #pragma unroll
    for (int j = 0; j < 4; ++j) {
        const int row = (w * 4 + j) * 8 + r8;
        const int m = mBase + row;
        u16x8 sa;
        if constexpr (AMODE == 1) {
            const float* ap = &A[(size_t)m * lda + swz];
            f32x4 x0 = *(const f32x4*)ap;
            f32x4 x1 = *(const f32x4*)(ap + 4);
            #pragma unroll
            for (int r = 0; r < 4; ++r) { sa[r] = f2bf(x0[r]); sa[4 + r] = f2bf(x1[r]); }
        } else {
            const int q = m & 2047, bb = m >> 11, hh = swz >> 6, dd = swz & 63;
            const size_t off = ((((size_t)((bb << 3) | hh)) * 2048 + q) << 6) + dd;
            f32x4 a0 = *(const f32x4*)&A [off];
            f32x4 a1 = *(const f32x4*)&A [off + 4];
            f32x4 c0 = *(const f32x4*)&A2[off];
            f32x4 c1 = *(const f32x4*)&A2[off + 4];
            const float rl = 1.f / (lp0[off >> 6] + lp1[off >> 6]);
            #pragma unroll
            for (int r = 0; r < 4; ++r) {
                sa[r]     = f2bf((a0[r] + c0[r]) * rl);
                sa[4 + r] = f2bf((a1[r] + c1[r]) * rl);
            }
        }
        *(u16x8*)&smA[(w * 4 + j) * 512 + lane * 8] = sa;
        gload16(&Bt[(size_t)(nBase + row) * K + swz], smB + (w * 4 + j) * 512);
    }
    __syncthreads();   // drains vmcnt (gload) + lgkm (ds_write): tile 0 ready

    int cur = 0;
    for (int t = 0; t < nsteps; ++t) {
        const int nxt = cur ^ 1;
        const int k1 = (t + 1) * 64;
        const bool more = (t + 1) < nsteps;

        // ---- 1. issue tile t+1 loads (A raw fp32 to regs; B gload to buf^1)
        f32x4 px0[4], px1[4], pc0[4], pc1[4];
        float pls[4];
        if (more) {
            #pragma unroll
            for (int j = 0; j < 4; ++j) {
                const int row = (w * 4 + j) * 8 + r8;
                const int m = mBase + row;
                const int kc = k1 + swz;
                if constexpr (AMODE == 1) {
                    const float* ap = &A[(size_t)m * lda + kc];
                    px0[j] = *(const f32x4*)ap;
                    px1[j] = *(const f32x4*)(ap + 4);
                } else {
                    const int q = m & 2047, bb = m >> 11, hh = kc >> 6, dd = kc & 63;
                    const size_t off = ((((size_t)((bb << 3) | hh)) * 2048 + q) << 6) + dd;
                    px0[j] = *(const f32x4*)&A [off];
                    px1[j] = *(const f32x4*)&A [off + 4];
                    pc0[j] = *(const f32x4*)&A2[off];
                    pc1[j] = *(const f32x4*)&A2[off + 4];
                    pls[j] = lp0[off >> 6] + lp1[off >> 6];
                }
                gload16(&Bt[(size_t)(nBase + row) * K + k1 + swz],
                        smB + nxt * 8192 + (w * 4 + j) * 512);
            }
        }

        // ---- 2. compute on buf[cur] ----
        const unsigned short* sA = smA + cur * 8192;
        const unsigned short* sB = smB + cur * 8192;
        #pragma unroll
        for (int kk = 0; kk < 64; kk += 32) {
            const int cb = kk >> 3;                     // chunk base: 0 or 4
            bf16x8 xa[4], wb[4];
            #pragma unroll
            for (int mt = 0; mt < 4; ++mt)
                xa[mt] = ldb8(&sA[(wm * 64 + mt * 16 + lanem) * 64 + (((cb + quad) ^ fxor) << 3)]);
            #pragma unroll
            for (int nt = 0; nt < 4; ++nt)
                wb[nt] = ldb8(&sB[(wn * 64 + nt * 16 + lanem) * 64 + (((cb + quad) ^ fxor) << 3)]);
            if constexpr (DIRECT) {
                #pragma unroll
                for (int mt = 0; mt < 4; ++mt)
                    #pragma unroll
                    for (int nt = 0; nt < 4; ++nt)
                        acc[mt][nt] = __builtin_amdgcn_mfma_f32_16x16x32_bf16(xa[mt], wb[nt], acc[mt][nt], 0, 0, 0);
            } else {
                #pragma unroll
                for (int nt = 0; nt < 4; ++nt)
                    #pragma unroll
                    for (int mt = 0; mt < 4; ++mt)
                        acc[nt][mt] = __builtin_amdgcn_mfma_f32_16x16x32_bf16(wb[nt], xa[mt], acc[nt][mt], 0, 0, 0);
            }
        }

        // ---- 3. convert + ds_write A(t+1) into buf^1 (loads landed by now)
        if (more) {
            #pragma unroll
            for (int j = 0; j < 4; ++j) {
                u16x8 sa;
                if constexpr (AMODE == 1) {
                    #pragma unroll
                    for (int r = 0; r < 4; ++r) { sa[r] = f2bf(px0[j][r]); sa[4 + r] = f2bf(px1[j][r]); }
                } else {
                    const float rl = 1.f / pls[j];
                    #pragma unroll
                    for (int r = 0; r < 4; ++r) {
                        sa[r]     = f2bf((px0[j][r] + pc0[j][r]) * rl);
                        sa[4 + r] = f2bf((px1[j][r] + pc1[j][r]) * rl);
                    }
                }
                *(u16x8*)&smA[nxt * 8192 + (w * 4 + j) * 512 + lane * 8] = sa;
            }
        }
        // ---- 4. single barrier: next tile ready; cur-read guard for t+1 ----
        __syncthreads();
        cur = nxt;
    }
}

// ---------------------------------------------------------------------------
// Fused QKV projection (cast fused into A-staging), 1-D grid of 768 blocks
// with XCD-COLOCATION swizzle (R6-verified: FETCH 146->46 MB): the 4
// nBase-blocks sharing an A row-panel (mBase,z) get the same id%8 -> same
// XCD -> shared fp32 A k-stripes are L2 hits.
//   id: xcd=id&7, j=id>>3; n=j&3, pr=j>>2; p=pr*8+xcd; z=p>>6, mIdx=p&63.
// z=0 Q (scaled), z=1 K, z=2 V->Vt.  A = raw fp32 query/key/value.
// ---------------------------------------------------------------------------
__global__ __launch_bounds__(256)
void gemm_qkv(const float* __restrict__ Xq, const float* __restrict__ Xk,
              const float* __restrict__ Xv, const unsigned short* __restrict__ Wt,
              const float* __restrict__ bq, const float* __restrict__ bk,
              const float* __restrict__ bv,
              unsigned short* __restrict__ Qb, unsigned short* __restrict__ Kb,
              unsigned short* __restrict__ Vtb)
{
    __shared__ unsigned short smA[2 * 128 * 64];
    __shared__ unsigned short smB[2 * 128 * 64];
    const int id = blockIdx.x;
    const int xcd = id & 7, j = id >> 3;
    const int nIdx = j & 3, pr = j >> 2;
    const int p = pr * 8 + xcd;            // 0..191
    const int z = p >> 6;                  // 0..2
    const int mBase = (p & 63) * 128, nBase = nIdx * 128;

    const float* A = z == 0 ? Xq : (z == 1 ? Xk : Xv);
    const unsigned short* Bt = Wt + (size_t)z * (EMB * DIMX);
    const float* bias = z == 0 ? bq : (z == 1 ? bk : bv);

    const int tid = threadIdx.x;
    const int lane = tid & 63, w = tid >> 6;
    const int quad = lane >> 4, lanem = lane & 15;
    const int wm = w >> 1, wn = w & 1;

    f32x4 acc[4][4];
    if (z == 2) {
        gemm_core<true, 1>(A, nullptr, nullptr, nullptr, Bt, DIMX, DIMX, mBase, nBase, smA, smB, acc);
        // V epilogue: write Vt[b][h][dh][s], 4 consecutive s per lane
        #pragma unroll
        for (int mt = 0; mt < 4; ++mt) {
            const int sg = mBase + wm * 64 + mt * 16 + quad * 4;
            const int b = sg >> 11, s = sg & 2047;
            #pragma unroll
            for (int nt = 0; nt < 4; ++nt) {
                const int de = nBase + wn * 64 + nt * 16 + lanem;
                const float bvv = bias[de];
                const int h = de >> 6, dh = de & 63;
                u16x4 ov;
                #pragma unroll
                for (int r = 0; r < 4; ++r) ov[r] = f2bf(acc[mt][nt][r] + bvv);
                *(u16x4*)&Vtb[((size_t)((b * NH + h) * HD + dh) << 11) + s] = ov;
            }
        }
    } else {
        gemm_core<false, 1>(A, nullptr, nullptr, nullptr, Bt, DIMX, DIMX, mBase, nBase, smA, smB, acc);
        const float os = (z == 0) ? 0.18033688f : 1.0f;   // Q: (1/8)*log2(e) folded
        unsigned short* C = (z == 0) ? Qb : Kb;
        #pragma unroll
        for (int nt = 0; nt < 4; ++nt) {
            const int n0 = nBase + wn * 64 + nt * 16 + quad * 4;
            const f32x4 b4 = *(const f32x4*)&bias[n0];
            #pragma unroll
            for (int mt = 0; mt < 4; ++mt) {
                const int m = mBase + wm * 64 + mt * 16 + lanem;
                u16x4 ov;
                #pragma unroll
                for (int r = 0; r < 4; ++r) ov[r] = f2bf((acc[nt][mt][r] + b4[r]) * os);
                *(u16x4*)&C[(size_t)m * EMB + n0] = ov;
            }
        }
    }
}

// ---------------------------------------------------------------------------
// Output projection with attn_reduce fused into A-staging, 1-D grid of 384
// blocks with the same XCD-colocation swizzle (6 nBase-blocks per m-panel):
//   xcd=id&7, j=id>>3 (0..47); n=j%6, pr=j/6; mIdx=pr*8+xcd.
//   A[m][k] = f2bf((Op0+Op1) / (l0+l1)), then @ Wot^T + bo -> fp32 out.
// ---------------------------------------------------------------------------
__global__ __launch_bounds__(256)
void gemm_out(const float* __restrict__ Opart, const float* __restrict__ lpart,
              const unsigned short* __restrict__ Wot,
              const float* __restrict__ bo, float* __restrict__ out)
{
    __shared__ unsigned short smA[2 * 128 * 64];
    __shared__ unsigned short smB[2 * 128 * 64];
    const int id = blockIdx.x;
    const int xcd = id & 7, j = id >> 3;
    const int nIdx = j % 6, pr = j / 6;
    const int mBase = (pr * 8 + xcd) * 128, nBase = nIdx * 128;
    const int tid = threadIdx.x;
    const int lane = tid & 63, w = tid >> 6;
    const int quad = lane >> 4, lanem = lane & 15;
    const int wm = w >> 1, wn = w & 1;

    const float* Op1 = Opart + (size_t)32 * SEQL * HD;
    const float* lp1 = lpart + (size_t)32 * SEQL;

    f32x4 acc[4][4];
    gemm_core<false, 2>(Opart, Op1, lpart, lp1, Wot, EMB, EMB, mBase, nBase, smA, smB, acc);
    #pragma unroll
    for (int nt = 0; nt < 4; ++nt) {
        const int n0 = nBase + wn * 64 + nt * 16 + quad * 4;
        const f32x4 b4 = *(const f32x4*)&bo[n0];
        #pragma unroll
        for (int mt = 0; mt < 4; ++mt) {
            const int m = mBase + wm * 64 + mt * 16 + lanem;
            f32x4 ov = acc[nt][mt] + b4;
            *(f32x4*)&out[(size_t)m * DIMX + n0] = ov;
        }
    }
}

// ---------------------------------------------------------------------------
// Fused flash attention, LDS-staged, SPLIT-K over the key dimension.
// (Round-0/3 structure, measured 54.5-56.5us — rounds 1/2 proved
// direct-from-global operand variants lose via barrier-drain latency + L1
// redundancy. FROZEN.)
// Grid 1024 blocks: (bh 32) x (qb 16) x (split 2), XCD-swizzled so blocks on
// one XCD share (b,h). Block = 256 thr = 4 waves; wave owns 32 q rows.
// Each block processes KSPAN=1024 keys and writes ADDITIVE partials
// (no-max softmax => partials combine by plain summation):
//   Opart[split][bh][q][d] fp32, lpart[split][bh][q] fp32.
// S^T = mfma(K,Q); P = exp2 (log2e/8 folded into Q), truncated bf16 pack;
// O^T = mfma(V^T,P); l via ones-row MFMA on the same truncated P.
// LDS tiles padded stride 72 (conflict-free b128).
// ---------------------------------------------------------------------------
__global__ __launch_bounds__(256)
void attn_mfma(const unsigned short* __restrict__ Qb, const unsigned short* __restrict__ Kb,
               const unsigned short* __restrict__ Vt,
               float* __restrict__ Opart, float* __restrict__ lpart)
{
    __shared__ unsigned short smK[64 * 72];
    __shared__ unsigned short smV[64 * 72];          // V^T tile: [d][k]
    __shared__ unsigned short smP[4][32 * 72];       // per-wave P tile: [q][k]
    const int id = blockIdx.x;
    const int bh = ((id & 7) << 2) | ((id >> 3) & 3);   // id%8 fixed -> same 4 bh per XCD
    const int rest = id >> 5;
    const int qb = rest & 15, sp = rest >> 4;
    const int b = bh >> 3, h = bh & 7;

    const int tid = threadIdx.x;
    const int w = tid >> 6, lane = tid & 63;
    const int quad = lane >> 4, lanem = lane & 15;

    // Q fragments (already scaled by (1/8)*log2(e) in projection)
    bf16x8 aq[2][2];
    #pragma unroll
    for (int rg = 0; rg < 2; ++rg) {
        const size_t qrow = (size_t)(b * SEQL + qb * 128 + w * 32 + rg * 16 + lanem) * EMB + h * HD;
        aq[rg][0] = ldb8(&Qb[qrow + quad * 8]);
        aq[rg][1] = ldb8(&Qb[qrow + 32 + quad * 8]);
    }

    const f32x4 z4 = {0.f, 0.f, 0.f, 0.f};
    f32x4 o[4][2];            // O^T accum [dt][rg]
    f32x4 ls[2] = {z4, z4};   // row-sum accum (ones-row MFMA)
    #pragma unroll
    for (int dt = 0; dt < 4; ++dt)
        #pragma unroll
        for (int rg = 0; rg < 2; ++rg) o[dt][rg] = z4;

    BF8 ones;
    #pragma unroll
    for (int i = 0; i < 8; ++i) ones.u[i] = 0x3F80;   // bf16 1.0

    const unsigned short* Kbase = Kb + (size_t)b * SEQL * EMB + h * HD;
    const unsigned short* Vbase = Vt + (size_t)bh * HD * SEQL;
    unsigned short* pW = &smP[w][0];
    const int srow = tid >> 3, c8 = (tid & 7) * 8;   // staging map (2 rows apart per p)

    for (int t = 0; t < KSPAN / 64; ++t) {
        const int k0 = sp * KSPAN + t * 64;
        u16x8 kv[2], vv[2];
        #pragma unroll
        for (int p = 0; p < 2; ++p) {
            kv[p] = *(const u16x8*)&Kbase[(size_t)(k0 + srow + p * 32) * EMB + c8];
            vv[p] = *(const u16x8*)&Vbase[(size_t)(srow + p * 32) * SEQL + k0 + c8];
        }
        __syncthreads();  // guard previous iteration's frag reads
        #pragma unroll
        for (int p = 0; p < 2; ++p) {
            *(u16x8*)&smK[(srow + p * 32) * 72 + c8] = kv[p];
            *(u16x8*)&smV[(srow + p * 32) * 72 + c8] = vv[p];
        }
        __syncthreads();

        // ---- S^T, exp2, truncated-pack P to LDS ----
        #pragma unroll
        for (int nt = 0; nt < 4; ++nt) {
            bf16x8 bk0 = ldb8(&smK[(nt * 16 + lanem) * 72 + quad * 8]);
            bf16x8 bk1 = ldb8(&smK[(nt * 16 + lanem) * 72 + 32 + quad * 8]);
            #pragma unroll
            for (int rg = 0; rg < 2; ++rg) {
                f32x4 s = __builtin_amdgcn_mfma_f32_16x16x32_bf16(bk0, aq[rg][0], z4, 0, 0, 0);
                s = __builtin_amdgcn_mfma_f32_16x16x32_bf16(bk1, aq[rg][1], s, 0, 0, 0);
                u16x4 pk;
                #pragma unroll
                for (int r = 0; r < 4; ++r)
                    pk[r] = (unsigned short)(__float_as_uint(EXP2F(s[r])) >> 16);
                *(u16x4*)&pW[(rg * 16 + lanem) * 72 + nt * 16 + quad * 4] = pk;
            }
        }
        // ---- P back as B-operand fragments (same wave; no barrier) ----
        bf16x8 pb[2][2];
        #pragma unroll
        for (int rg = 0; rg < 2; ++rg) {
            pb[rg][0] = ldb8(&pW[(rg * 16 + lanem) * 72 + quad * 8]);
            pb[rg][1] = ldb8(&pW[(rg * 16 + lanem) * 72 + 32 + quad * 8]);
        }
        // ---- O^T += V^T @ P^T ; l += ones @ P^T ----
        #pragma unroll
        for (int dt = 0; dt < 4; ++dt) {
            bf16x8 av0 = ldb8(&smV[(dt * 16 + lanem) * 72 + quad * 8]);
            bf16x8 av1 = ldb8(&smV[(dt * 16 + lanem) * 72 + 32 + quad * 8]);
            #pragma unroll
            for (int rg = 0; rg < 2; ++rg) {
                o[dt][rg] = __builtin_amdgcn_mfma_f32_16x16x32_bf16(av0, pb[rg][0], o[dt][rg], 0, 0, 0);
                o[dt][rg] = __builtin_amdgcn_mfma_f32_16x16x32_bf16(av1, pb[rg][1], o[dt][rg], 0, 0, 0);
            }
        }
        #pragma unroll
        for (int rg = 0; rg < 2; ++rg) {
            ls[rg] = __builtin_amdgcn_mfma_f32_16x16x32_bf16(ones.b, pb[rg][0], ls[rg], 0, 0, 0);
            ls[rg] = __builtin_amdgcn_mfma_f32_16x16x32_bf16(ones.b, pb[rg][1], ls[rg], 0, 0, 0);
        }
    }

    // epilogue: additive fp32 partials. O^T: col=q=lanem, row=d=dt*16+quad*4+r.
    #pragma unroll
    for (int rg = 0; rg < 2; ++rg) {
        const int qloc = qb * 128 + w * 32 + rg * 16 + lanem;
        float* orow = Opart + ((size_t)sp * 32 * SEQL + (size_t)bh * SEQL + qloc) * HD;
        #pragma unroll
        for (int dt = 0; dt < 4; ++dt)
            *(f32x4*)&orow[dt * 16 + quad * 4] = o[dt][rg];
        if (quad == 0)
            lpart[(size_t)sp * 32 * SEQL + (size_t)bh * SEQL + qloc] = ls[rg][0];
    }
}

// ---------------------------------------------------------------------------
extern "C" void kernel_launch(void* const* d_in, const int* in_sizes, int n_in,
                              void* d_out, int out_size, void* d_ws, size_t ws_size,
                              hipStream_t stream) {
    (void)in_sizes; (void)n_in; (void)out_size; (void)ws_size;
    const float* query = (const float*)d_in[0];
    const float* key   = (const float*)d_in[1];
    const float* value = (const float*)d_in[2];
    const float* wq = (const float*)d_in[3];
    const float* bq = (const float*)d_in[4];
    const float* wk = (const float*)d_in[5];
    const float* bk = (const float*)d_in[6];
    const float* wv = (const float*)d_in[7];
    const float* bv = (const float*)d_in[8];
    const float* wo = (const float*)d_in[9];
    const float* bo = (const float*)d_in[10];
    float* out = (float*)d_out;

    char* ws = (char*)d_ws;
    float*          Opart = (float*)(ws);                       // 33,554,432 B
    float*          lpart = (float*)(ws + 33554432);            //    524,288 B
    unsigned short* Wt    = (unsigned short*)(ws + 37748736);   //  2,359,296 B
    unsigned short* Wot   = (unsigned short*)(ws + 40108032);   //    786,432 B
    unsigned short* Qbuf  = (unsigned short*)(ws + 40894464);   //  8,388,608 B
    unsigned short* Kbuf  = (unsigned short*)(ws + 49283072);   //  8,388,608 B
    unsigned short* Vtb   = (unsigned short*)(ws + 57671680);   //  8,388,608 B -> ends 66,060,288

    const dim3 blk(256);

    transpose_w4<<<dim3(384, 4), blk, 0, stream>>>(wq, wk, wv, wo,
        Wt, Wt + (size_t)EMB * DIMX, Wt + 2 * (size_t)EMB * DIMX, Wot);

    gemm_qkv<<<dim3(768), blk, 0, stream>>>(
        query, key, value, Wt, bq, bk, bv, Qbuf, Kbuf, Vtb);

    attn_mfma<<<dim3(32 * 16 * NSPLIT), blk, 0, stream>>>(Qbuf, Kbuf, Vtb, Opart, lpart);

    gemm_out<<<dim3(384), blk, 0, stream>>>(Opart, lpart, Wot, bo, out);
}

// Round 8
// 238.197 us; speedup vs baseline: 1.0950x; 1.0950x over previous
//
#include <hip/hip_runtime.h>
#include <math.h>

#define NH   8
#define HD   64
#define BS   4
#define SEQL 2048
#define DIMX 768
#define EMB  512
#define MROWS (BS*SEQL)
#define NSPLIT 2
#define KSPAN (SEQL/NSPLIT)

typedef __attribute__((ext_vector_type(4))) float          f32x4;
typedef __attribute__((ext_vector_type(8))) __bf16         bf16x8;
typedef __attribute__((ext_vector_type(8))) unsigned short u16x8;
typedef __attribute__((ext_vector_type(4))) unsigned short u16x4;

union BF8 { u16x8 u; bf16x8 b; };

__device__ __forceinline__ unsigned short f2bf(float x) {   // RNE
    unsigned int u = __float_as_uint(x);
    u += 0x7FFFu + ((u >> 16) & 1u);
    return (unsigned short)(u >> 16);
}

#if __has_builtin(__builtin_amdgcn_exp2f)
#define EXP2F(x) __builtin_amdgcn_exp2f(x)
#else
#define EXP2F(x) exp2f(x)
#endif

__device__ __forceinline__ bf16x8 ldb8(const unsigned short* p) {
    return *(const bf16x8*)p;
}

// Async global->LDS, 16B per lane. LDS dest is wave-uniform base + lane*16
// (HW semantics); global src is per-lane.
__device__ __forceinline__ void gload16(const unsigned short* g, unsigned short* l) {
    __builtin_amdgcn_global_load_lds(
        (const __attribute__((address_space(1))) unsigned int*)(const void*)g,
        (__attribute__((address_space(3))) unsigned int*)(void*)l,
        16, 0, 0);
}

// ---------------------------------------------------------------------------
// All 4 weight transposes in ONE dispatch: fp32 [R][C] -> bf16 [C][R].
// ---------------------------------------------------------------------------
__global__ __launch_bounds__(256)
void transpose_w4(const float* __restrict__ w0, const float* __restrict__ w1,
                  const float* __restrict__ w2, const float* __restrict__ w3,
                  unsigned short* __restrict__ o0, unsigned short* __restrict__ o1,
                  unsigned short* __restrict__ o2, unsigned short* __restrict__ o3)
{
    __shared__ float sm[32][33];
    const int which = blockIdx.y;
    const float* in; unsigned short* out; int R, C;
    if      (which == 0) { in = w0; out = o0; R = DIMX; C = EMB;  }
    else if (which == 1) { in = w1; out = o1; R = DIMX; C = EMB;  }
    else if (which == 2) { in = w2; out = o2; R = DIMX; C = EMB;  }
    else                 { in = w3; out = o3; R = EMB;  C = DIMX; }
    const int nbx = C / 32;
    const int rB = (blockIdx.x / nbx) * 32, cB = (blockIdx.x % nbx) * 32;
    const int row = threadIdx.x >> 3, c4 = (threadIdx.x & 7) * 4;
    f32x4 v = *(const f32x4*)&in[(size_t)(rB + row) * C + cB + c4];
    sm[row][c4 + 0] = v[0]; sm[row][c4 + 1] = v[1];
    sm[row][c4 + 2] = v[2]; sm[row][c4 + 3] = v[3];
    __syncthreads();
    u16x4 o;
    o[0] = f2bf(sm[c4 + 0][row]); o[1] = f2bf(sm[c4 + 1][row]);
    o[2] = f2bf(sm[c4 + 2][row]); o[3] = f2bf(sm[c4 + 3][row]);
    *(u16x4*)&out[(size_t)(cB + row) * R + rB + c4] = o;
}

// ---------------------------------------------------------------------------
// Shared GEMM core, ROUND-8: BM=64 x BN=128 tile, BK=64, 256 thr (4 waves
// as 2x2: wave owns 32 rows x 64 cols). R6's 2-barrier single-buffer
// structure (R7 proved dbuf+64KB LDS loses via occupancy; R6-vs-R3 proved
// staging mechanics don't bind). Halving BM doubles the grid -> 6 blocks/CU
// (LDS 24KB) to hide the exposed A-load/gload latency chain with TLP,
// which R6 counters showed as the bind (MfmaUtil 10%, occ 14%, 4300
// cyc/K-step vs ~500 compute).
// B staging: gload16 into linear LDS [128][64], rule-#21 both-sides swizzle
//   (pre-XORed global source column chunk^row&7; XORed frag reads).
// A staging FUSED-ON-THE-FLY, ds_write path with the same swizzle:
//   AMODE 1: A fp32 [M][lda], cast bf16 RNE during staging (kills cast3).
//   AMODE 2: A[m][k] = f2bf((Op0+Op1) * 1/(l0+l1)) attn split-combine
//            (kills attn_reduce), Opart layout [sp][bh][q][64].
// acc flattened [8]: DIRECT idx mt*4+nt (row=m, col=n, V-transposed
// epilogue); !DIRECT idx nt*2+mt (row=n, col=m, packed row-major out).
// ---------------------------------------------------------------------------
template<bool DIRECT, int AMODE>
__device__ __forceinline__ void gemm_core64(
    const float* __restrict__ A, const float* __restrict__ A2,
    const float* __restrict__ lp0, const float* __restrict__ lp1,
    const unsigned short* __restrict__ Bt,
    int K, int lda, int mBase, int nBase,
    unsigned short* __restrict__ smA,   // [64][64] bf16, 8KB
    unsigned short* __restrict__ smB,   // [128][64] bf16, 16KB
    f32x4 (&acc)[8])
{
    const int tid = threadIdx.x;
    const int lane = tid & 63, w = tid >> 6;
    const int quad = lane >> 4, lanem = lane & 15;
    const int wm = w >> 1, wn = w & 1;
    // staging lane map: r8=row-in-slab (8 rows/slab), ch=16B chunk;
    // global col chunk pre-XORed by row&7 (rule #21).
    const int r8 = lane >> 3, ch = lane & 7;
    const int swz = ((ch ^ r8) << 3);          // element offset within row
    const int fxor = (lanem & 7);              // frag-read XOR (row&7)

    const f32x4 z4 = {0.f, 0.f, 0.f, 0.f};
    #pragma unroll
    for (int i = 0; i < 8; ++i) acc[i] = z4;

    for (int k0 = 0; k0 < K; k0 += 64) {
        // ---- compute staged A values in regs (loads issue before barrier;
        //      latency overlaps other waves/blocks) ----
        u16x8 sa[2];
        #pragma unroll
        for (int j = 0; j < 2; ++j) {          // A: 2 slabs/wave (64 rows tot)
            const int m = mBase + (w * 2 + j) * 8 + r8;
            const int kc = k0 + swz;
            if constexpr (AMODE == 1) {
                const float* ap = &A[(size_t)m * lda + kc];
                f32x4 x0 = *(const f32x4*)ap;
                f32x4 x1 = *(const f32x4*)(ap + 4);
                #pragma unroll
                for (int r = 0; r < 4; ++r) { sa[j][r] = f2bf(x0[r]); sa[j][4 + r] = f2bf(x1[r]); }
            } else {
                // AMODE 2: split-combine + normalize.  bh = b*8 + h, h = kc>>6
                const int q = m & 2047, bb = m >> 11, hh = kc >> 6, dd = kc & 63;
                const size_t off = ((((size_t)((bb << 3) | hh)) * 2048 + q) << 6) + dd;
                f32x4 a0 = *(const f32x4*)&A [off];
                f32x4 a1 = *(const f32x4*)&A [off + 4];
                f32x4 c0 = *(const f32x4*)&A2[off];
                f32x4 c1 = *(const f32x4*)&A2[off + 4];
                const float rl = 1.f / (lp0[off >> 6] + lp1[off >> 6]);
                #pragma unroll
                for (int r = 0; r < 4; ++r) {
                    sa[j][r]     = f2bf((a0[r] + c0[r]) * rl);
                    sa[j][4 + r] = f2bf((a1[r] + c1[r]) * rl);
                }
            }
        }
        __syncthreads();   // guard previous iteration's frag reads
        #pragma unroll
        for (int j = 0; j < 2; ++j)
            *(u16x8*)&smA[(w * 2 + j) * 512 + lane * 8] = sa[j];
        #pragma unroll
        for (int j = 0; j < 4; ++j) {          // B: 4 slabs/wave (128 rows tot)
            const int row = (w * 4 + j) * 8 + r8;
            gload16(&Bt[(size_t)(nBase + row) * K + k0 + swz], smB + (w * 4 + j) * 512);
        }
        __syncthreads();   // drains vmcnt (gload) + lgkm (ds_write)
        #pragma unroll
        for (int kk = 0; kk < 64; kk += 32) {
            const int cb = kk >> 3;                     // chunk base: 0 or 4
            bf16x8 xa[2], wb[4];
            #pragma unroll
            for (int mt = 0; mt < 2; ++mt)
                xa[mt] = ldb8(&smA[(wm * 32 + mt * 16 + lanem) * 64 + (((cb + quad) ^ fxor) << 3)]);
            #pragma unroll
            for (int nt = 0; nt < 4; ++nt)
                wb[nt] = ldb8(&smB[(wn * 64 + nt * 16 + lanem) * 64 + (((cb + quad) ^ fxor) << 3)]);
            if constexpr (DIRECT) {
                #pragma unroll
                for (int mt = 0; mt < 2; ++mt)
                    #pragma unroll
                    for (int nt = 0; nt < 4; ++nt)
                        acc[mt * 4 + nt] = __builtin_amdgcn_mfma_f32_16x16x32_bf16(xa[mt], wb[nt], acc[mt * 4 + nt], 0, 0, 0);
            } else {
                #pragma unroll
                for (int nt = 0; nt < 4; ++nt)
                    #pragma unroll
                    for (int mt = 0; mt < 2; ++mt)
                        acc[nt * 2 + mt] = __builtin_amdgcn_mfma_f32_16x16x32_bf16(wb[nt], xa[mt], acc[nt * 2 + mt], 0, 0, 0);
            }
        }
    }
}

// ---------------------------------------------------------------------------
// Fused QKV projection (cast fused into A-staging), 1-D grid of 1536 blocks
// (BM=64 -> 6 blocks/CU) with XCD-COLOCATION swizzle (R6-verified:
// FETCH 146->46 MB): the 4 nBase-blocks sharing an A row-panel (mBase,z)
// get the same id%8 -> same XCD -> shared fp32 A k-stripes are L2 hits.
//   id: xcd=id&7, j=id>>3 (0..191); n=j&3, pr=j>>2; p=pr*8+xcd (0..383);
//   z=p>>7, mIdx=p&127.
// z=0 Q (scaled), z=1 K, z=2 V->Vt.  A = raw fp32 query/key/value.
// ---------------------------------------------------------------------------
__global__ __launch_bounds__(256)
void gemm_qkv(const float* __restrict__ Xq, const float* __restrict__ Xk,
              const float* __restrict__ Xv, const unsigned short* __restrict__ Wt,
              const float* __restrict__ bq, const float* __restrict__ bk,
              const float* __restrict__ bv,
              unsigned short* __restrict__ Qb, unsigned short* __restrict__ Kb,
              unsigned short* __restrict__ Vtb)
{
    __shared__ unsigned short smA[64 * 64];
    __shared__ unsigned short smB[128 * 64];
    const int id = blockIdx.x;
    const int xcd = id & 7, j = id >> 3;
    const int nIdx = j & 3, pr = j >> 2;
    const int p = pr * 8 + xcd;            // 0..383
    const int z = p >> 7;                  // 0..2
    const int mBase = (p & 127) * 64, nBase = nIdx * 128;

    const float* A = z == 0 ? Xq : (z == 1 ? Xk : Xv);
    const unsigned short* Bt = Wt + (size_t)z * (EMB * DIMX);
    const float* bias = z == 0 ? bq : (z == 1 ? bk : bv);

    const int tid = threadIdx.x;
    const int lane = tid & 63, w = tid >> 6;
    const int quad = lane >> 4, lanem = lane & 15;
    const int wm = w >> 1, wn = w & 1;

    f32x4 acc[8];
    if (z == 2) {
        gemm_core64<true, 1>(A, nullptr, nullptr, nullptr, Bt, DIMX, DIMX, mBase, nBase, smA, smB, acc);
        // V epilogue: write Vt[b][h][dh][s], 4 consecutive s per lane
        #pragma unroll
        for (int mt = 0; mt < 2; ++mt) {
            const int sg = mBase + wm * 32 + mt * 16 + quad * 4;
            const int b = sg >> 11, s = sg & 2047;
            #pragma unroll
            for (int nt = 0; nt < 4; ++nt) {
                const int de = nBase + wn * 64 + nt * 16 + lanem;
                const float bvv = bias[de];
                const int h = de >> 6, dh = de & 63;
                u16x4 ov;
                #pragma unroll
                for (int r = 0; r < 4; ++r) ov[r] = f2bf(acc[mt * 4 + nt][r] + bvv);
                *(u16x4*)&Vtb[((size_t)((b * NH + h) * HD + dh) << 11) + s] = ov;
            }
        }
    } else {
        gemm_core64<false, 1>(A, nullptr, nullptr, nullptr, Bt, DIMX, DIMX, mBase, nBase, smA, smB, acc);
        const float os = (z == 0) ? 0.18033688f : 1.0f;   // Q: (1/8)*log2(e) folded
        unsigned short* C = (z == 0) ? Qb : Kb;
        #pragma unroll
        for (int nt = 0; nt < 4; ++nt) {
            const int n0 = nBase + wn * 64 + nt * 16 + quad * 4;
            const f32x4 b4 = *(const f32x4*)&bias[n0];
            #pragma unroll
            for (int mt = 0; mt < 2; ++mt) {
                const int m = mBase + wm * 32 + mt * 16 + lanem;
                u16x4 ov;
                #pragma unroll
                for (int r = 0; r < 4; ++r) ov[r] = f2bf((acc[nt * 2 + mt][r] + b4[r]) * os);
                *(u16x4*)&C[(size_t)m * EMB + n0] = ov;
            }
        }
    }
}

// ---------------------------------------------------------------------------
// Output projection with attn_reduce fused into A-staging, 1-D grid of 768
// blocks (BM=64 -> 3 blocks/CU, was 1.5) with the same XCD-colocation
// swizzle (6 nBase-blocks per m-panel):
//   xcd=id&7, j=id>>3 (0..95); n=j%6, pr=j/6 (0..15); mIdx=pr*8+xcd.
//   A[m][k] = f2bf((Op0+Op1) / (l0+l1)), then @ Wot^T + bo -> fp32 out.
// ---------------------------------------------------------------------------
__global__ __launch_bounds__(256)
void gemm_out(const float* __restrict__ Opart, const float* __restrict__ lpart,
              const unsigned short* __restrict__ Wot,
              const float* __restrict__ bo, float* __restrict__ out)
{
    __shared__ unsigned short smA[64 * 64];
    __shared__ unsigned short smB[128 * 64];
    const int id = blockIdx.x;
    const int xcd = id & 7, j = id >> 3;
    const int nIdx = j % 6, pr = j / 6;
    const int mBase = (pr * 8 + xcd) * 64, nBase = nIdx * 128;
    const int tid = threadIdx.x;
    const int lane = tid & 63, w = tid >> 6;
    const int quad = lane >> 4, lanem = lane & 15;
    const int wm = w >> 1, wn = w & 1;

    const float* Op1 = Opart + (size_t)32 * SEQL * HD;
    const float* lp1 = lpart + (size_t)32 * SEQL;

    f32x4 acc[8];
    gemm_core64<false, 2>(Opart, Op1, lpart, lp1, Wot, EMB, EMB, mBase, nBase, smA, smB, acc);
    #pragma unroll
    for (int nt = 0; nt < 4; ++nt) {
        const int n0 = nBase + wn * 64 + nt * 16 + quad * 4;
        const f32x4 b4 = *(const f32x4*)&bo[n0];
        #pragma unroll
        for (int mt = 0; mt < 2; ++mt) {
            const int m = mBase + wm * 32 + mt * 16 + lanem;
            f32x4 ov = acc[nt * 2 + mt] + b4;
            *(f32x4*)&out[(size_t)m * DIMX + n0] = ov;
        }
    }
}

// ---------------------------------------------------------------------------
// Fused flash attention, LDS-staged, SPLIT-K over the key dimension.
// (Round-0/3 structure, measured 54.5-56.5us — rounds 1/2 proved
// direct-from-global operand variants lose via barrier-drain latency + L1
// redundancy. FROZEN.)
// Grid 1024 blocks: (bh 32) x (qb 16) x (split 2), XCD-swizzled so blocks on
// one XCD share (b,h). Block = 256 thr = 4 waves; wave owns 32 q rows.
// Each block processes KSPAN=1024 keys and writes ADDITIVE partials
// (no-max softmax => partials combine by plain summation):
//   Opart[split][bh][q][d] fp32, lpart[split][bh][q] fp32.
// S^T = mfma(K,Q); P = exp2 (log2e/8 folded into Q), truncated bf16 pack;
// O^T = mfma(V^T,P); l via ones-row MFMA on the same truncated P.
// LDS tiles padded stride 72 (conflict-free b128).
// ---------------------------------------------------------------------------
__global__ __launch_bounds__(256)
void attn_mfma(const unsigned short* __restrict__ Qb, const unsigned short* __restrict__ Kb,
               const unsigned short* __restrict__ Vt,
               float* __restrict__ Opart, float* __restrict__ lpart)
{
    __shared__ unsigned short smK[64 * 72];
    __shared__ unsigned short smV[64 * 72];          // V^T tile: [d][k]
    __shared__ unsigned short smP[4][32 * 72];       // per-wave P tile: [q][k]
    const int id = blockIdx.x;
    const int bh = ((id & 7) << 2) | ((id >> 3) & 3);   // id%8 fixed -> same 4 bh per XCD
    const int rest = id >> 5;
    const int qb = rest & 15, sp = rest >> 4;
    const int b = bh >> 3, h = bh & 7;

    const int tid = threadIdx.x;
    const int w = tid >> 6, lane = tid & 63;
    const int quad = lane >> 4, lanem = lane & 15;

    // Q fragments (already scaled by (1/8)*log2(e) in projection)
    bf16x8 aq[2][2];
    #pragma unroll
    for (int rg = 0; rg < 2; ++rg) {
        const size_t qrow = (size_t)(b * SEQL + qb * 128 + w * 32 + rg * 16 + lanem) * EMB + h * HD;
        aq[rg][0] = ldb8(&Qb[qrow + quad * 8]);
        aq[rg][1] = ldb8(&Qb[qrow + 32 + quad * 8]);
    }

    const f32x4 z4 = {0.f, 0.f, 0.f, 0.f};
    f32x4 o[4][2];            // O^T accum [dt][rg]
    f32x4 ls[2] = {z4, z4};   // row-sum accum (ones-row MFMA)
    #pragma unroll
    for (int dt = 0; dt < 4; ++dt)
        #pragma unroll
        for (int rg = 0; rg < 2; ++rg) o[dt][rg] = z4;

    BF8 ones;
    #pragma unroll
    for (int i = 0; i < 8; ++i) ones.u[i] = 0x3F80;   // bf16 1.0

    const unsigned short* Kbase = Kb + (size_t)b * SEQL * EMB + h * HD;
    const unsigned short* Vbase = Vt + (size_t)bh * HD * SEQL;
    unsigned short* pW = &smP[w][0];
    const int srow = tid >> 3, c8 = (tid & 7) * 8;   // staging map (2 rows apart per p)

    for (int t = 0; t < KSPAN / 64; ++t) {
        const int k0 = sp * KSPAN + t * 64;
        u16x8 kv[2], vv[2];
        #pragma unroll
        for (int p = 0; p < 2; ++p) {
            kv[p] = *(const u16x8*)&Kbase[(size_t)(k0 + srow + p * 32) * EMB + c8];
            vv[p] = *(const u16x8*)&Vbase[(size_t)(srow + p * 32) * SEQL + k0 + c8];
        }
        __syncthreads();  // guard previous iteration's frag reads
        #pragma unroll
        for (int p = 0; p < 2; ++p) {
            *(u16x8*)&smK[(srow + p * 32) * 72 + c8] = kv[p];
            *(u16x8*)&smV[(srow + p * 32) * 72 + c8] = vv[p];
        }
        __syncthreads();

        // ---- S^T, exp2, truncated-pack P to LDS ----
        #pragma unroll
        for (int nt = 0; nt < 4; ++nt) {
            bf16x8 bk0 = ldb8(&smK[(nt * 16 + lanem) * 72 + quad * 8]);
            bf16x8 bk1 = ldb8(&smK[(nt * 16 + lanem) * 72 + 32 + quad * 8]);
            #pragma unroll
            for (int rg = 0; rg < 2; ++rg) {
                f32x4 s = __builtin_amdgcn_mfma_f32_16x16x32_bf16(bk0, aq[rg][0], z4, 0, 0, 0);
                s = __builtin_amdgcn_mfma_f32_16x16x32_bf16(bk1, aq[rg][1], s, 0, 0, 0);
                u16x4 pk;
                #pragma unroll
                for (int r = 0; r < 4; ++r)
                    pk[r] = (unsigned short)(__float_as_uint(EXP2F(s[r])) >> 16);
                *(u16x4*)&pW[(rg * 16 + lanem) * 72 + nt * 16 + quad * 4] = pk;
            }
        }
        // ---- P back as B-operand fragments (same wave; no barrier) ----
        bf16x8 pb[2][2];
        #pragma unroll
        for (int rg = 0; rg < 2; ++rg) {
            pb[rg][0] = ldb8(&pW[(rg * 16 + lanem) * 72 + quad * 8]);
            pb[rg][1] = ldb8(&pW[(rg * 16 + lanem) * 72 + 32 + quad * 8]);
        }
        // ---- O^T += V^T @ P^T ; l += ones @ P^T ----
        #pragma unroll
        for (int dt = 0; dt < 4; ++dt) {
            bf16x8 av0 = ldb8(&smV[(dt * 16 + lanem) * 72 + quad * 8]);
            bf16x8 av1 = ldb8(&smV[(dt * 16 + lanem) * 72 + 32 + quad * 8]);
            #pragma unroll
            for (int rg = 0; rg < 2; ++rg) {
                o[dt][rg] = __builtin_amdgcn_mfma_f32_16x16x32_bf16(av0, pb[rg][0], o[dt][rg], 0, 0, 0);
                o[dt][rg] = __builtin_amdgcn_mfma_f32_16x16x32_bf16(av1, pb[rg][1], o[dt][rg], 0, 0, 0);
            }
        }
        #pragma unroll
        for (int rg = 0; rg < 2; ++rg) {
            ls[rg] = __builtin_amdgcn_mfma_f32_16x16x32_bf16(ones.b, pb[rg][0], ls[rg], 0, 0, 0);
            ls[rg] = __builtin_amdgcn_mfma_f32_16x16x32_bf16(ones.b, pb[rg][1], ls[rg], 0, 0, 0);
        }
    }

    // epilogue: additive fp32 partials. O^T: col=q=lanem, row=d=dt*16+quad*4+r.
    #pragma unroll
    for (int rg = 0; rg < 2; ++rg) {
        const int qloc = qb * 128 + w * 32 + rg * 16 + lanem;
        float* orow = Opart + ((size_t)sp * 32 * SEQL + (size_t)bh * SEQL + qloc) * HD;
        #pragma unroll
        for (int dt = 0; dt < 4; ++dt)
            *(f32x4*)&orow[dt * 16 + quad * 4] = o[dt][rg];
        if (quad == 0)
            lpart[(size_t)sp * 32 * SEQL + (size_t)bh * SEQL + qloc] = ls[rg][0];
    }
}

// ---------------------------------------------------------------------------
extern "C" void kernel_launch(void* const* d_in, const int* in_sizes, int n_in,
                              void* d_out, int out_size, void* d_ws, size_t ws_size,
                              hipStream_t stream) {
    (void)in_sizes; (void)n_in; (void)out_size; (void)ws_size;
    const float* query = (const float*)d_in[0];
    const float* key   = (const float*)d_in[1];
    const float* value = (const float*)d_in[2];
    const float* wq = (const float*)d_in[3];
    const float* bq = (const float*)d_in[4];
    const float* wk = (const float*)d_in[5];
    const float* bk = (const float*)d_in[6];
    const float* wv = (const float*)d_in[7];
    const float* bv = (const float*)d_in[8];
    const float* wo = (const float*)d_in[9];
    const float* bo = (const float*)d_in[10];
    float* out = (float*)d_out;

    char* ws = (char*)d_ws;
    float*          Opart = (float*)(ws);                       // 33,554,432 B
    float*          lpart = (float*)(ws + 33554432);            //    524,288 B
    unsigned short* Wt    = (unsigned short*)(ws + 37748736);   //  2,359,296 B
    unsigned short* Wot   = (unsigned short*)(ws + 40108032);   //    786,432 B
    unsigned short* Qbuf  = (unsigned short*)(ws + 40894464);   //  8,388,608 B
    unsigned short* Kbuf  = (unsigned short*)(ws + 49283072);   //  8,388,608 B
    unsigned short* Vtb   = (unsigned short*)(ws + 57671680);   //  8,388,608 B -> ends 66,060,288

    const dim3 blk(256);

    transpose_w4<<<dim3(384, 4), blk, 0, stream>>>(wq, wk, wv, wo,
        Wt, Wt + (size_t)EMB * DIMX, Wt + 2 * (size_t)EMB * DIMX, Wot);

    gemm_qkv<<<dim3(1536), blk, 0, stream>>>(
        query, key, value, Wt, bq, bk, bv, Qbuf, Kbuf, Vtb);

    attn_mfma<<<dim3(32 * 16 * NSPLIT), blk, 0, stream>>>(Qbuf, Kbuf, Vtb, Opart, lpart);

    gemm_out<<<dim3(768), blk, 0, stream>>>(Opart, lpart, Wot, bo, out);
}

// Round 9
// 233.277 us; speedup vs baseline: 1.1181x; 1.0211x over previous
//
#include <hip/hip_runtime.h>
#include <math.h>

#define NH   8
#define HD   64
#define BS   4
#define SEQL 2048
#define DIMX 768
#define EMB  512
#define MROWS (BS*SEQL)
#define NSPLIT 2
#define KSPAN (SEQL/NSPLIT)

typedef __attribute__((ext_vector_type(4))) float          f32x4;
typedef __attribute__((ext_vector_type(8))) __bf16         bf16x8;
typedef __attribute__((ext_vector_type(8))) unsigned short u16x8;
typedef __attribute__((ext_vector_type(4))) unsigned short u16x4;

union BF8 { u16x8 u; bf16x8 b; };

__device__ __forceinline__ unsigned short f2bf(float x) {   // RNE
    unsigned int u = __float_as_uint(x);
    u += 0x7FFFu + ((u >> 16) & 1u);
    return (unsigned short)(u >> 16);
}

#if __has_builtin(__builtin_amdgcn_exp2f)
#define EXP2F(x) __builtin_amdgcn_exp2f(x)
#else
#define EXP2F(x) exp2f(x)
#endif

__device__ __forceinline__ bf16x8 ldb8(const unsigned short* p) {
    return *(const bf16x8*)p;
}

// Async global->LDS, 16B per lane. LDS dest is wave-uniform base + lane*16
// (HW semantics); global src is per-lane.
__device__ __forceinline__ void gload16(const unsigned short* g, unsigned short* l) {
    __builtin_amdgcn_global_load_lds(
        (const __attribute__((address_space(1))) unsigned int*)(const void*)g,
        (__attribute__((address_space(3))) unsigned int*)(void*)l,
        16, 0, 0);
}

// ---------------------------------------------------------------------------
// All 4 weight transposes in ONE dispatch: fp32 [R][C] -> bf16 [C][R].
// ---------------------------------------------------------------------------
__global__ __launch_bounds__(256)
void transpose_w4(const float* __restrict__ w0, const float* __restrict__ w1,
                  const float* __restrict__ w2, const float* __restrict__ w3,
                  unsigned short* __restrict__ o0, unsigned short* __restrict__ o1,
                  unsigned short* __restrict__ o2, unsigned short* __restrict__ o3)
{
    __shared__ float sm[32][33];
    const int which = blockIdx.y;
    const float* in; unsigned short* out; int R, C;
    if      (which == 0) { in = w0; out = o0; R = DIMX; C = EMB;  }
    else if (which == 1) { in = w1; out = o1; R = DIMX; C = EMB;  }
    else if (which == 2) { in = w2; out = o2; R = DIMX; C = EMB;  }
    else                 { in = w3; out = o3; R = EMB;  C = DIMX; }
    const int nbx = C / 32;
    const int rB = (blockIdx.x / nbx) * 32, cB = (blockIdx.x % nbx) * 32;
    const int row = threadIdx.x >> 3, c4 = (threadIdx.x & 7) * 4;
    f32x4 v = *(const f32x4*)&in[(size_t)(rB + row) * C + cB + c4];
    sm[row][c4 + 0] = v[0]; sm[row][c4 + 1] = v[1];
    sm[row][c4 + 2] = v[2]; sm[row][c4 + 3] = v[3];
    __syncthreads();
    u16x4 o;
    o[0] = f2bf(sm[c4 + 0][row]); o[1] = f2bf(sm[c4 + 1][row]);
    o[2] = f2bf(sm[c4 + 2][row]); o[3] = f2bf(sm[c4 + 3][row]);
    *(u16x4*)&out[(size_t)(cB + row) * R + rB + c4] = o;
}

// ---------------------------------------------------------------------------
// Shared GEMM core, ROUND-8/9: BM=64 x BN=128 tile, BK=64, 256 thr (4 waves
// as 2x2: wave owns 32 rows x 64 cols), single-buffer 2-barrier structure
// (R7 proved dbuf loses via occupancy; R6-vs-R3 proved staging mechanics
// don't bind; R8-vs-R6 proved the real cap was the VGPR-64 occupancy step).
// B staging: gload16 into linear LDS [128][64], rule-#21 both-sides swizzle
//   (pre-XORed global source column chunk^row&7; XORed frag reads).
// A staging FUSED-ON-THE-FLY, ds_write path with the same swizzle:
//   AMODE 1: A fp32 [M][lda], cast bf16 RNE during staging (kills cast3).
//   AMODE 2: A[m][k] = f2bf((Op0+Op1) * 1/(l0+l1)) attn split-combine
//            (kills attn_reduce), Opart layout [sp][bh][q][64].
// acc flattened [8]: DIRECT idx mt*4+nt (row=m, col=n, V-transposed
// epilogue); !DIRECT idx nt*2+mt (row=n, col=m, packed row-major out).
// ---------------------------------------------------------------------------
template<bool DIRECT, int AMODE>
__device__ __forceinline__ void gemm_core64(
    const float* __restrict__ A, const float* __restrict__ A2,
    const float* __restrict__ lp0, const float* __restrict__ lp1,
    const unsigned short* __restrict__ Bt,
    int K, int lda, int mBase, int nBase,
    unsigned short* __restrict__ smA,   // [64][64] bf16, 8KB
    unsigned short* __restrict__ smB,   // [128][64] bf16, 16KB
    f32x4 (&acc)[8])
{
    const int tid = threadIdx.x;
    const int lane = tid & 63, w = tid >> 6;
    const int quad = lane >> 4, lanem = lane & 15;
    const int wm = w >> 1, wn = w & 1;
    // staging lane map: r8=row-in-slab (8 rows/slab), ch=16B chunk;
    // global col chunk pre-XORed by row&7 (rule #21).
    const int r8 = lane >> 3, ch = lane & 7;
    const int swz = ((ch ^ r8) << 3);          // element offset within row
    const int fxor = (lanem & 7);              // frag-read XOR (row&7)

    const f32x4 z4 = {0.f, 0.f, 0.f, 0.f};
    #pragma unroll
    for (int i = 0; i < 8; ++i) acc[i] = z4;

    for (int k0 = 0; k0 < K; k0 += 64) {
        // ---- compute staged A values in regs (loads issue before barrier;
        //      latency overlaps other waves/blocks) ----
        u16x8 sa[2];
        #pragma unroll
        for (int j = 0; j < 2; ++j) {          // A: 2 slabs/wave (64 rows tot)
            const int m = mBase + (w * 2 + j) * 8 + r8;
            const int kc = k0 + swz;
            if constexpr (AMODE == 1) {
                const float* ap = &A[(size_t)m * lda + kc];
                f32x4 x0 = *(const f32x4*)ap;
                f32x4 x1 = *(const f32x4*)(ap + 4);
                #pragma unroll
                for (int r = 0; r < 4; ++r) { sa[j][r] = f2bf(x0[r]); sa[j][4 + r] = f2bf(x1[r]); }
            } else {
                // AMODE 2: split-combine + normalize.  bh = b*8 + h, h = kc>>6
                const int q = m & 2047, bb = m >> 11, hh = kc >> 6, dd = kc & 63;
                const size_t off = ((((size_t)((bb << 3) | hh)) * 2048 + q) << 6) + dd;
                f32x4 a0 = *(const f32x4*)&A [off];
                f32x4 a1 = *(const f32x4*)&A [off + 4];
                f32x4 c0 = *(const f32x4*)&A2[off];
                f32x4 c1 = *(const f32x4*)&A2[off + 4];
                const float rl = 1.f / (lp0[off >> 6] + lp1[off >> 6]);
                #pragma unroll
                for (int r = 0; r < 4; ++r) {
                    sa[j][r]     = f2bf((a0[r] + c0[r]) * rl);
                    sa[j][4 + r] = f2bf((a1[r] + c1[r]) * rl);
                }
            }
        }
        __syncthreads();   // guard previous iteration's frag reads
        #pragma unroll
        for (int j = 0; j < 2; ++j)
            *(u16x8*)&smA[(w * 2 + j) * 512 + lane * 8] = sa[j];
        #pragma unroll
        for (int j = 0; j < 4; ++j) {          // B: 4 slabs/wave (128 rows tot)
            const int row = (w * 4 + j) * 8 + r8;
            gload16(&Bt[(size_t)(nBase + row) * K + k0 + swz], smB + (w * 4 + j) * 512);
        }
        __syncthreads();   // drains vmcnt (gload) + lgkm (ds_write)
        #pragma unroll
        for (int kk = 0; kk < 64; kk += 32) {
            const int cb = kk >> 3;                     // chunk base: 0 or 4
            bf16x8 xa[2], wb[4];
            #pragma unroll
            for (int mt = 0; mt < 2; ++mt)
                xa[mt] = ldb8(&smA[(wm * 32 + mt * 16 + lanem) * 64 + (((cb + quad) ^ fxor) << 3)]);
            #pragma unroll
            for (int nt = 0; nt < 4; ++nt)
                wb[nt] = ldb8(&smB[(wn * 64 + nt * 16 + lanem) * 64 + (((cb + quad) ^ fxor) << 3)]);
            if constexpr (DIRECT) {
                #pragma unroll
                for (int mt = 0; mt < 2; ++mt)
                    #pragma unroll
                    for (int nt = 0; nt < 4; ++nt)
                        acc[mt * 4 + nt] = __builtin_amdgcn_mfma_f32_16x16x32_bf16(xa[mt], wb[nt], acc[mt * 4 + nt], 0, 0, 0);
            } else {
                #pragma unroll
                for (int nt = 0; nt < 4; ++nt)
                    #pragma unroll
                    for (int mt = 0; mt < 2; ++mt)
                        acc[nt * 2 + mt] = __builtin_amdgcn_mfma_f32_16x16x32_bf16(wb[nt], xa[mt], acc[nt * 2 + mt], 0, 0, 0);
            }
        }
    }
}

// ---------------------------------------------------------------------------
// Fused QKV projection (cast fused into A-staging), 1-D grid of 1536 blocks
// with XCD-COLOCATION swizzle (R6-verified: FETCH 146->46 MB).
// ROUND-9: __launch_bounds__(256, 8) forces VGPR <= 64. R8 measured
// VGPR_Count=68, which crosses the 64-VGPR occupancy step (waves/CU halve
// at 64/128/256) -> HW capped residency at 4 blocks/CU while the grid
// wants 6 -> 1.5 sequential rounds + tail. At <=64 VGPR the cap is 8;
// LDS 24KB caps 6 -> all 6 resident in one round.
//   id: xcd=id&7, j=id>>3 (0..191); n=j&3, pr=j>>2; p=pr*8+xcd (0..383);
//   z=p>>7, mIdx=p&127.
// z=0 Q (scaled), z=1 K, z=2 V->Vt.  A = raw fp32 query/key/value.
// ---------------------------------------------------------------------------
__global__ __launch_bounds__(256, 8)
void gemm_qkv(const float* __restrict__ Xq, const float* __restrict__ Xk,
              const float* __restrict__ Xv, const unsigned short* __restrict__ Wt,
              const float* __restrict__ bq, const float* __restrict__ bk,
              const float* __restrict__ bv,
              unsigned short* __restrict__ Qb, unsigned short* __restrict__ Kb,
              unsigned short* __restrict__ Vtb)
{
    __shared__ unsigned short smA[64 * 64];
    __shared__ unsigned short smB[128 * 64];
    const int id = blockIdx.x;
    const int xcd = id & 7, j = id >> 3;
    const int nIdx = j & 3, pr = j >> 2;
    const int p = pr * 8 + xcd;            // 0..383
    const int z = p >> 7;                  // 0..2
    const int mBase = (p & 127) * 64, nBase = nIdx * 128;

    const float* A = z == 0 ? Xq : (z == 1 ? Xk : Xv);
    const unsigned short* Bt = Wt + (size_t)z * (EMB * DIMX);
    const float* bias = z == 0 ? bq : (z == 1 ? bk : bv);

    const int tid = threadIdx.x;
    const int lane = tid & 63, w = tid >> 6;
    const int quad = lane >> 4, lanem = lane & 15;
    const int wm = w >> 1, wn = w & 1;

    f32x4 acc[8];
    if (z == 2) {
        gemm_core64<true, 1>(A, nullptr, nullptr, nullptr, Bt, DIMX, DIMX, mBase, nBase, smA, smB, acc);
        // V epilogue: write Vt[b][h][dh][s], 4 consecutive s per lane
        #pragma unroll
        for (int mt = 0; mt < 2; ++mt) {
            const int sg = mBase + wm * 32 + mt * 16 + quad * 4;
            const int b = sg >> 11, s = sg & 2047;
            #pragma unroll
            for (int nt = 0; nt < 4; ++nt) {
                const int de = nBase + wn * 64 + nt * 16 + lanem;
                const float bvv = bias[de];
                const int h = de >> 6, dh = de & 63;
                u16x4 ov;
                #pragma unroll
                for (int r = 0; r < 4; ++r) ov[r] = f2bf(acc[mt * 4 + nt][r] + bvv);
                *(u16x4*)&Vtb[((size_t)((b * NH + h) * HD + dh) << 11) + s] = ov;
            }
        }
    } else {
        gemm_core64<false, 1>(A, nullptr, nullptr, nullptr, Bt, DIMX, DIMX, mBase, nBase, smA, smB, acc);
        const float os = (z == 0) ? 0.18033688f : 1.0f;   // Q: (1/8)*log2(e) folded
        unsigned short* C = (z == 0) ? Qb : Kb;
        #pragma unroll
        for (int nt = 0; nt < 4; ++nt) {
            const int n0 = nBase + wn * 64 + nt * 16 + quad * 4;
            const f32x4 b4 = *(const f32x4*)&bias[n0];
            #pragma unroll
            for (int mt = 0; mt < 2; ++mt) {
                const int m = mBase + wm * 32 + mt * 16 + lanem;
                u16x4 ov;
                #pragma unroll
                for (int r = 0; r < 4; ++r) ov[r] = f2bf((acc[nt * 2 + mt][r] + b4[r]) * os);
                *(u16x4*)&C[(size_t)m * EMB + n0] = ov;
            }
        }
    }
}

// ---------------------------------------------------------------------------
// Output projection with attn_reduce fused into A-staging, 1-D grid of 768
// blocks (3 blocks/CU -- already under the 4-block VGPR cap, so no
// launch_bounds forcing here; AMODE2's extra live registers make a forced
// 64-VGPR fit a spill hazard) with the same XCD-colocation swizzle
// (6 nBase-blocks per m-panel):
//   xcd=id&7, j=id>>3 (0..95); n=j%6, pr=j/6 (0..15); mIdx=pr*8+xcd.
//   A[m][k] = f2bf((Op0+Op1) / (l0+l1)), then @ Wot^T + bo -> fp32 out.
// ---------------------------------------------------------------------------
__global__ __launch_bounds__(256)
void gemm_out(const float* __restrict__ Opart, const float* __restrict__ lpart,
              const unsigned short* __restrict__ Wot,
              const float* __restrict__ bo, float* __restrict__ out)
{
    __shared__ unsigned short smA[64 * 64];
    __shared__ unsigned short smB[128 * 64];
    const int id = blockIdx.x;
    const int xcd = id & 7, j = id >> 3;
    const int nIdx = j % 6, pr = j / 6;
    const int mBase = (pr * 8 + xcd) * 64, nBase = nIdx * 128;
    const int tid = threadIdx.x;
    const int lane = tid & 63, w = tid >> 6;
    const int quad = lane >> 4, lanem = lane & 15;
    const int wm = w >> 1, wn = w & 1;

    const float* Op1 = Opart + (size_t)32 * SEQL * HD;
    const float* lp1 = lpart + (size_t)32 * SEQL;

    f32x4 acc[8];
    gemm_core64<false, 2>(Opart, Op1, lpart, lp1, Wot, EMB, EMB, mBase, nBase, smA, smB, acc);
    #pragma unroll
    for (int nt = 0; nt < 4; ++nt) {
        const int n0 = nBase + wn * 64 + nt * 16 + quad * 4;
        const f32x4 b4 = *(const f32x4*)&bo[n0];
        #pragma unroll
        for (int mt = 0; mt < 2; ++mt) {
            const int m = mBase + wm * 32 + mt * 16 + lanem;
            f32x4 ov = acc[nt * 2 + mt] + b4;
            *(f32x4*)&out[(size_t)m * DIMX + n0] = ov;
        }
    }
}

// ---------------------------------------------------------------------------
// Fused flash attention, LDS-staged, SPLIT-K over the key dimension.
// (Round-0/3 structure, measured 54.5-56.5us — rounds 1/2 proved
// direct-from-global operand variants lose via barrier-drain latency + L1
// redundancy. FROZEN.)
// Grid 1024 blocks: (bh 32) x (qb 16) x (split 2), XCD-swizzled so blocks on
// one XCD share (b,h). Block = 256 thr = 4 waves; wave owns 32 q rows.
// Each block processes KSPAN=1024 keys and writes ADDITIVE partials
// (no-max softmax => partials combine by plain summation):
//   Opart[split][bh][q][d] fp32, lpart[split][bh][q] fp32.
// S^T = mfma(K,Q); P = exp2 (log2e/8 folded into Q), truncated bf16 pack;
// O^T = mfma(V^T,P); l via ones-row MFMA on the same truncated P.
// LDS tiles padded stride 72 (conflict-free b128).
// ---------------------------------------------------------------------------
__global__ __launch_bounds__(256)
void attn_mfma(const unsigned short* __restrict__ Qb, const unsigned short* __restrict__ Kb,
               const unsigned short* __restrict__ Vt,
               float* __restrict__ Opart, float* __restrict__ lpart)
{
    __shared__ unsigned short smK[64 * 72];
    __shared__ unsigned short smV[64 * 72];          // V^T tile: [d][k]
    __shared__ unsigned short smP[4][32 * 72];       // per-wave P tile: [q][k]
    const int id = blockIdx.x;
    const int bh = ((id & 7) << 2) | ((id >> 3) & 3);   // id%8 fixed -> same 4 bh per XCD
    const int rest = id >> 5;
    const int qb = rest & 15, sp = rest >> 4;
    const int b = bh >> 3, h = bh & 7;

    const int tid = threadIdx.x;
    const int w = tid >> 6, lane = tid & 63;
    const int quad = lane >> 4, lanem = lane & 15;

    // Q fragments (already scaled by (1/8)*log2(e) in projection)
    bf16x8 aq[2][2];
    #pragma unroll
    for (int rg = 0; rg < 2; ++rg) {
        const size_t qrow = (size_t)(b * SEQL + qb * 128 + w * 32 + rg * 16 + lanem) * EMB + h * HD;
        aq[rg][0] = ldb8(&Qb[qrow + quad * 8]);
        aq[rg][1] = ldb8(&Qb[qrow + 32 + quad * 8]);
    }

    const f32x4 z4 = {0.f, 0.f, 0.f, 0.f};
    f32x4 o[4][2];            // O^T accum [dt][rg]
    f32x4 ls[2] = {z4, z4};   // row-sum accum (ones-row MFMA)
    #pragma unroll
    for (int dt = 0; dt < 4; ++dt)
        #pragma unroll
        for (int rg = 0; rg < 2; ++rg) o[dt][rg] = z4;

    BF8 ones;
    #pragma unroll
    for (int i = 0; i < 8; ++i) ones.u[i] = 0x3F80;   // bf16 1.0

    const unsigned short* Kbase = Kb + (size_t)b * SEQL * EMB + h * HD;
    const unsigned short* Vbase = Vt + (size_t)bh * HD * SEQL;
    unsigned short* pW = &smP[w][0];
    const int srow = tid >> 3, c8 = (tid & 7) * 8;   // staging map (2 rows apart per p)

    for (int t = 0; t < KSPAN / 64; ++t) {
        const int k0 = sp * KSPAN + t * 64;
        u16x8 kv[2], vv[2];
        #pragma unroll
        for (int p = 0; p < 2; ++p) {
            kv[p] = *(const u16x8*)&Kbase[(size_t)(k0 + srow + p * 32) * EMB + c8];
            vv[p] = *(const u16x8*)&Vbase[(size_t)(srow + p * 32) * SEQL + k0 + c8];
        }
        __syncthreads();  // guard previous iteration's frag reads
        #pragma unroll
        for (int p = 0; p < 2; ++p) {
            *(u16x8*)&smK[(srow + p * 32) * 72 + c8] = kv[p];
            *(u16x8*)&smV[(srow + p * 32) * 72 + c8] = vv[p];
        }
        __syncthreads();

        // ---- S^T, exp2, truncated-pack P to LDS ----
        #pragma unroll
        for (int nt = 0; nt < 4; ++nt) {
            bf16x8 bk0 = ldb8(&smK[(nt * 16 + lanem) * 72 + quad * 8]);
            bf16x8 bk1 = ldb8(&smK[(nt * 16 + lanem) * 72 + 32 + quad * 8]);
            #pragma unroll
            for (int rg = 0; rg < 2; ++rg) {
                f32x4 s = __builtin_amdgcn_mfma_f32_16x16x32_bf16(bk0, aq[rg][0], z4, 0, 0, 0);
                s = __builtin_amdgcn_mfma_f32_16x16x32_bf16(bk1, aq[rg][1], s, 0, 0, 0);
                u16x4 pk;
                #pragma unroll
                for (int r = 0; r < 4; ++r)
                    pk[r] = (unsigned short)(__float_as_uint(EXP2F(s[r])) >> 16);
                *(u16x4*)&pW[(rg * 16 + lanem) * 72 + nt * 16 + quad * 4] = pk;
            }
        }
        // ---- P back as B-operand fragments (same wave; no barrier) ----
        bf16x8 pb[2][2];
        #pragma unroll
        for (int rg = 0; rg < 2; ++rg) {
            pb[rg][0] = ldb8(&pW[(rg * 16 + lanem) * 72 + quad * 8]);
            pb[rg][1] = ldb8(&pW[(rg * 16 + lanem) * 72 + 32 + quad * 8]);
        }
        // ---- O^T += V^T @ P^T ; l += ones @ P^T ----
        #pragma unroll
        for (int dt = 0; dt < 4; ++dt) {
            bf16x8 av0 = ldb8(&smV[(dt * 16 + lanem) * 72 + quad * 8]);
            bf16x8 av1 = ldb8(&smV[(dt * 16 + lanem) * 72 + 32 + quad * 8]);
            #pragma unroll
            for (int rg = 0; rg < 2; ++rg) {
                o[dt][rg] = __builtin_amdgcn_mfma_f32_16x16x32_bf16(av0, pb[rg][0], o[dt][rg], 0, 0, 0);
                o[dt][rg] = __builtin_amdgcn_mfma_f32_16x16x32_bf16(av1, pb[rg][1], o[dt][rg], 0, 0, 0);
            }
        }
        #pragma unroll
        for (int rg = 0; rg < 2; ++rg) {
            ls[rg] = __builtin_amdgcn_mfma_f32_16x16x32_bf16(ones.b, pb[rg][0], ls[rg], 0, 0, 0);
            ls[rg] = __builtin_amdgcn_mfma_f32_16x16x32_bf16(ones.b, pb[rg][1], ls[rg], 0, 0, 0);
        }
    }

    // epilogue: additive fp32 partials. O^T: col=q=lanem, row=d=dt*16+quad*4+r.
    #pragma unroll
    for (int rg = 0; rg < 2; ++rg) {
        const int qloc = qb * 128 + w * 32 + rg * 16 + lanem;
        float* orow = Opart + ((size_t)sp * 32 * SEQL + (size_t)bh * SEQL + qloc) * HD;
        #pragma unroll
        for (int dt = 0; dt < 4; ++dt)
            *(f32x4*)&orow[dt * 16 + quad * 4] = o[dt][rg];
        if (quad == 0)
            lpart[(size_t)sp * 32 * SEQL + (size_t)bh * SEQL + qloc] = ls[rg][0];
    }
}

// ---------------------------------------------------------------------------
extern "C" void kernel_launch(void* const* d_in, const int* in_sizes, int n_in,
                              void* d_out, int out_size, void* d_ws, size_t ws_size,
                              hipStream_t stream) {
    (void)in_sizes; (void)n_in; (void)out_size; (void)ws_size;
    const float* query = (const float*)d_in[0];
    const float* key   = (const float*)d_in[1];
    const float* value = (const float*)d_in[2];
    const float* wq = (const float*)d_in[3];
    const float* bq = (const float*)d_in[4];
    const float* wk = (const float*)d_in[5];
    const float* bk = (const float*)d_in[6];
    const float* wv = (const float*)d_in[7];
    const float* bv = (const float*)d_in[8];
    const float* wo = (const float*)d_in[9];
    const float* bo = (const float*)d_in[10];
    float* out = (float*)d_out;

    char* ws = (char*)d_ws;
    float*          Opart = (float*)(ws);                       // 33,554,432 B
    float*          lpart = (float*)(ws + 33554432);            //    524,288 B
    unsigned short* Wt    = (unsigned short*)(ws + 37748736);   //  2,359,296 B
    unsigned short* Wot   = (unsigned short*)(ws + 40108032);   //    786,432 B
    unsigned short* Qbuf  = (unsigned short*)(ws + 40894464);   //  8,388,608 B
    unsigned short* Kbuf  = (unsigned short*)(ws + 49283072);   //  8,388,608 B
    unsigned short* Vtb   = (unsigned short*)(ws + 57671680);   //  8,388,608 B -> ends 66,060,288

    const dim3 blk(256);

    transpose_w4<<<dim3(384, 4), blk, 0, stream>>>(wq, wk, wv, wo,
        Wt, Wt + (size_t)EMB * DIMX, Wt + 2 * (size_t)EMB * DIMX, Wot);

    gemm_qkv<<<dim3(1536), blk, 0, stream>>>(
        query, key, value, Wt, bq, bk, bv, Qbuf, Kbuf, Vtb);

    attn_mfma<<<dim3(32 * 16 * NSPLIT), blk, 0, stream>>>(Qbuf, Kbuf, Vtb, Opart, lpart);

    gemm_out<<<dim3(768), blk, 0, stream>>>(Opart, lpart, Wot, bo, out);
}